// Round 8
// baseline (8843.948 us; speedup 1.0000x reference)
//
#include <hip/hip_runtime.h>
#include <hip/hip_bf16.h>
#include <cstddef>

#define S_LEN 512
#define BATCH 64
#define HID 256
#define G3 768
#define SB (S_LEN*BATCH)
#define D2 512
#define L2E 1.44269504f

typedef unsigned short u16;
typedef __attribute__((ext_vector_type(8))) short s16x8;
typedef __attribute__((ext_vector_type(8))) _Float16 f16x8;
typedef __attribute__((ext_vector_type(4))) float f32x4;

__device__ __forceinline__ float bf2f(u16 u) {
    return __uint_as_float(((unsigned)u) << 16);
}
__device__ __forceinline__ u16 f2bf(float f) {
    unsigned u = __float_as_uint(f);
    unsigned r = (u + 0x7FFFu + ((u >> 16) & 1u)) >> 16;
    return (u16)r;
}
__device__ __forceinline__ float fast_rcp(float x) {
#if __has_builtin(__builtin_amdgcn_rcpf)
    return __builtin_amdgcn_rcpf(x);
#else
    return 1.f / x;
#endif
}
__device__ __forceinline__ float fast_exp2(float x) {
#if __has_builtin(__builtin_amdgcn_exp2f)
    return __builtin_amdgcn_exp2f(x);
#else
    return __expf(x * 0.69314718f);
#endif
}
__device__ __forceinline__ void gload_lds16(const void* g, void* l) {
    __builtin_amdgcn_global_load_lds((const __attribute__((address_space(1))) void*)g,
                                     (__attribute__((address_space(3))) void*)l, 16, 0, 0);
}
__device__ __forceinline__ void bar_lgkm() {
    asm volatile("s_waitcnt lgkmcnt(0)" ::: "memory");
    __builtin_amdgcn_s_barrier();
    __builtin_amdgcn_sched_barrier(0);
}

// ---------- prep kernels ----------
__global__ void f32_to_bf16(const float* __restrict__ in, u16* __restrict__ out, long n) {
    long i = (long)blockIdx.x * 256 + threadIdx.x;
    if (i < n) out[i] = f2bf(in[i]);
}
// w_ih scaled: gate rows g<512 ×log2e, g>=512 ×2log2e (exp2 prescale)
__global__ void f32_to_bf16_gs(const float* __restrict__ in, u16* __restrict__ out,
                               long n, int K) {
    long i = (long)blockIdx.x * 256 + threadIdx.x;
    if (i >= n) return;
    int g = (int)((i / K) % 768);
    float sc = (g < 512) ? L2E : (2.f * L2E);
    out[i] = f2bf(in[i] * sc);
}
// w_hh scaled likewise, to f16
__global__ void f32_to_f16_gs(const float* __restrict__ in, _Float16* __restrict__ out, long n) {
    long i = (long)blockIdx.x * 256 + threadIdx.x;
    if (i >= n) return;
    int g = (int)((i / 256) % 768);
    float sc = (g < 512) ? L2E : (2.f * L2E);
    out[i] = (_Float16)(in[i] * sc);
}
// biasT[l][d][g]: g<512 -> (b_ih+b_hh)*log2e ; g>=512 -> b_ih*2log2e
// (b_hh_n stays INSIDE the r* product, handled in scan)
__global__ void add_bias(const float* __restrict__ bih0, const float* __restrict__ bihl,
                         const float* __restrict__ bhh, float* __restrict__ outb) {
    int i = blockIdx.x * 256 + threadIdx.x;
    if (i >= 6 * 1536) return;
    int l = i / 1536, r = i - l * 1536;
    int g = r % 768;
    float bi = (l == 0) ? bih0[r] : bihl[(l - 1) * 1536 + r];
    outb[i] = (g < 512) ? (bi + bhh[i]) * L2E : bi * (2.f * L2E);
}

// ---------- input GEMM (MFMA) ----------
__global__ __launch_bounds__(256, 2) void gemm_mfma(
    const u16* __restrict__ A,
    const u16* __restrict__ Bt,
    const float* __restrict__ bias,
    u16* __restrict__ Cg,
    int K)
{
    int d = blockIdx.z;
    const u16* Bb = Bt + (size_t)d * 768 * K;
    const float* bi = bias + d * G3;
    u16* Cm = Cg + (size_t)d * SB * G3;

    int n0 = blockIdx.x * 128;
    int m0 = blockIdx.y * 128;
    int tid = threadIdx.x;
    int wave = tid >> 6, lane = tid & 63;
    int wm = wave >> 1, wn = wave & 1;

    __shared__ u16 Asm[128 * 32];
    __shared__ u16 Bsm[128 * 32];

    f32x4 acc[4][4] = {};

    for (int k0 = 0; k0 < K; k0 += 32) {
#pragma unroll
        for (int p = 0; p < 2; p++) {
            int c = p * 256 + wave * 64 + lane;
            int row = c >> 2, kc = c & 3;
            const u16* srcA = A + (size_t)(m0 + row) * K + k0 + kc * 8;
            const u16* srcB = Bb + (size_t)(n0 + row) * K + k0 + kc * 8;
            gload_lds16(srcA, &Asm[(p * 256 + wave * 64) * 8]);
            gload_lds16(srcB, &Bsm[(p * 256 + wave * 64) * 8]);
        }
        __syncthreads();

        s16x8 af[4], bfr[4];
#pragma unroll
        for (int i = 0; i < 4; i++) {
            int arow = wm * 64 + i * 16 + (lane & 15);
            af[i] = *reinterpret_cast<const s16x8*>(&Asm[arow * 32 + (lane >> 4) * 8]);
            int brow = wn * 64 + i * 16 + (lane & 15);
            bfr[i] = *reinterpret_cast<const s16x8*>(&Bsm[brow * 32 + (lane >> 4) * 8]);
        }
#pragma unroll
        for (int i = 0; i < 4; i++)
#pragma unroll
            for (int j = 0; j < 4; j++)
                acc[i][j] = __builtin_amdgcn_mfma_f32_16x16x32_bf16(af[i], bfr[j], acc[i][j], 0, 0, 0);
        __syncthreads();
    }

    int lcol = lane & 15, lrow4 = (lane >> 4) * 4;
#pragma unroll
    for (int i = 0; i < 4; i++) {
#pragma unroll
        for (int j = 0; j < 4; j++) {
            int n = n0 + wn * 64 + j * 16 + lcol;
            float bv = bi[n];
#pragma unroll
            for (int q = 0; q < 4; q++) {
                int m = m0 + wm * 64 + i * 16 + lrow4 + q;
                Cm[(size_t)m * G3 + n] = f2bf(acc[i][j][q] + bv);
            }
        }
    }
}

// ---------- MFMA recurrent scan (v3) ----------
// 8 blocks (4 batch-groups x 2 dirs), 512 threads. Weights persistent in regs.
// gi: reg-staged 2 steps ahead, XOR-swizzled LDS (conflict-free), double-buffered.
// h: f16 LDS double-buffer. ONE barrier/step, NO vmcnt waits in loop.
__global__ __launch_bounds__(512, 2) void scan_mfma(
    const _Float16* __restrict__ whh16,  // [12][768][256] f16, exp2-prescaled
    const u16* __restrict__ gi,          // [2][SB][768] bf16, prescaled, r/z b_hh folded
    const float* __restrict__ bhh,       // [6][2][768] f32 raw (n-gate term)
    const float* __restrict__ h0,        // [12][64][256] f32
    u16* __restrict__ outc,              // [SB][512] bf16 (scratch on last layer)
    float* __restrict__ finals,          // [12][64][256] f32
    int layer)
{
    int b0 = blockIdx.x * 16;
    int d  = blockIdx.y;
    int ld = layer * 2 + d;
    int tid = threadIdx.x;
    int wv = tid >> 6, lane = tid & 63;
    int lr = lane & 15;
    int lq = lane >> 4;
    int r0 = lq * 4;

    // flat LDS: h 2x4096 f16 (16KB) + gi 2x12288 u16 (48KB) = 64KiB exactly
    __shared__ alignas(16) _Float16 hf[2 * 4096];
    __shared__ alignas(16) u16 gf[2 * 12288];

    const _Float16* Wl = whh16 + (size_t)ld * G3 * HID;
    const u16* gid = gi + (size_t)d * (size_t)SB * G3;

    // ---- persistent weight B-frags
    f16x8 bfrag[6][8];
#pragma unroll
    for (int i = 0; i < 6; i++) {
        int nt = (i & 1) ? (8 + wv) + (i >> 1) * 16 : wv + (i >> 1) * 16;
        int g = nt * 16 + lr;
#pragma unroll
        for (int kt = 0; kt < 8; kt++)
            bfrag[i][kt] = *reinterpret_cast<const f16x8*>(Wl + (size_t)g * HID + kt * 32 + lq * 8);
    }

    int c0 = wv * 16 + lr;
    int c1 = c0 + 128;
    float bhn0 = bhh[(size_t)ld * G3 + 512 + c0] * (2.f * L2E);
    float bhn1 = bhh[(size_t)ld * G3 + 512 + c1] * (2.f * L2E);

    // h layout (per buffer, f16 idx): (c>>3)*128 + row*8 + (c&7)  [= kt*512+lqslot*128+row*8+sub]
    float hreg0[4], hreg1[4];
    int hwb0 = (c0 >> 3) * 128 + lq * 32 + (c0 & 7);   // + q*8 ; c1 adds +2048
#pragma unroll
    for (int q = 0; q < 4; q++) {
        float hv0 = h0[(size_t)ld * BATCH * HID + (b0 + r0 + q) * HID + c0];
        float hv1 = h0[(size_t)ld * BATCH * HID + (b0 + r0 + q) * HID + c1];
        hreg0[q] = hv0; hreg1[q] = hv1;
        hf[hwb0 + q * 8] = (_Float16)hv0;
        hf[hwb0 + 2048 + q * 8] = (_Float16)hv1;
    }

    // ---- gi swizzled staging: dst u16 idx (per buffer), col ^= ((row>>2)&3)<<4
    int xr = ((wv >> 1) & 3) << 4;
    int dst0 = (2 * wv) * G3 + ((lane * 8) ^ xr);                       // row 2wv, col lane*8
    int dst1 = (lane < 32) ? (2 * wv) * G3 + ((512 + lane * 8) ^ xr)
                           : (2 * wv + 1) * G3 + ((lane * 8 - 256) ^ xr);
    int dst2 = (2 * wv + 1) * G3 + ((256 + lane * 8) ^ xr);

    uint4 greg0, greg1, greg2;
    {
        int s0 = d ? (S_LEN - 1) : 0;
        const u16* gp = gid + ((size_t)s0 * BATCH + b0) * G3 + wv * 1536 + lane * 8;
        uint4 a0 = *(const uint4*)gp;
        uint4 a1 = *(const uint4*)(gp + 512);
        uint4 a2 = *(const uint4*)(gp + 1024);
        *(uint4*)&gf[dst0] = a0;
        *(uint4*)&gf[dst1] = a1;
        *(uint4*)&gf[dst2] = a2;
        int s1 = d ? (S_LEN - 2) : 1;
        gp = gid + ((size_t)s1 * BATCH + b0) * G3 + wv * 1536 + lane * 8;
        greg0 = *(const uint4*)gp;
        greg1 = *(const uint4*)(gp + 512);
        greg2 = *(const uint4*)(gp + 1024);
    }
    __syncthreads();

    // per-lane gi read base (u16 idx, per buffer): row=lq*4 -> lq*3072; col c0 swizzled
    const int grb = lq * 3072 + (c0 ^ (lq << 4));   // + q*768 + gate*256 (+128 for c1)

    auto step_body = [&](int t, const int par) {
        int s = d ? (S_LEN - 1 - t) : t;
        // 1. write gi(t+1) -> buf par^1 (compiler auto-waits the loads)
        if (t + 1 < S_LEN) {
            *(uint4*)&gf[(par ^ 1) * 12288 + dst0] = greg0;
            *(uint4*)&gf[(par ^ 1) * 12288 + dst1] = greg1;
            *(uint4*)&gf[(par ^ 1) * 12288 + dst2] = greg2;
        }
        // 2. issue loads gi(t+2)
        if (t + 2 < S_LEN) {
            int s2 = d ? (s - 2) : (s + 2);
            const u16* gp = gid + ((size_t)s2 * BATCH + b0) * G3 + wv * 1536 + lane * 8;
            greg0 = *(const uint4*)gp;
            greg1 = *(const uint4*)(gp + 512);
            greg2 = *(const uint4*)(gp + 1024);
        }
        // 3. gate matmul: h_tiles[par] x bfrag
        f32x4 acc[6] = {};
#pragma unroll
        for (int kt = 0; kt < 8; kt++) {
            f16x8 a = *(const f16x8*)&hf[par * 4096 + kt * 512 + lq * 128 + lr * 8];
#pragma unroll
            for (int i = 0; i < 6; i++)
                acc[i] = __builtin_amdgcn_mfma_f32_16x16x32_f16(a, bfrag[i][kt], acc[i], 0, 0, 0);
        }
        // 4. GRU update: read gi buf par (swizzled, conflict-free), write h -> buf par^1
        const u16* gbp = &gf[par * 12288 + grb];
        size_t ob = ((size_t)s * BATCH + b0 + r0) * D2 + d * HID;
#pragma unroll
        for (int q = 0; q < 4; q++) {
            {
                float gir = bf2f(gbp[q * G3]);
                float giz = bf2f(gbp[q * G3 + 256]);
                float gin = bf2f(gbp[q * G3 + 512]);
                float r = fast_rcp(1.f + fast_exp2(-(gir + acc[0][q])));
                float z = fast_rcp(1.f + fast_exp2(-(giz + acc[2][q])));
                float xn = gin + r * (acc[4][q] + bhn0);
                float n = 1.f - 2.f * fast_rcp(fast_exp2(xn) + 1.f);
                float hn = n + z * (hreg0[q] - n);
                hreg0[q] = hn;
                hf[(par ^ 1) * 4096 + hwb0 + q * 8] = (_Float16)hn;
                outc[ob + q * D2 + c0] = f2bf(hn);
            }
            {
                float gir = bf2f(gbp[q * G3 + 128]);
                float giz = bf2f(gbp[q * G3 + 384]);
                float gin = bf2f(gbp[q * G3 + 640]);
                float r = fast_rcp(1.f + fast_exp2(-(gir + acc[1][q])));
                float z = fast_rcp(1.f + fast_exp2(-(giz + acc[3][q])));
                float xn = gin + r * (acc[5][q] + bhn1);
                float n = 1.f - 2.f * fast_rcp(fast_exp2(xn) + 1.f);
                float hn = n + z * (hreg1[q] - n);
                hreg1[q] = hn;
                hf[(par ^ 1) * 4096 + hwb0 + 2048 + q * 8] = (_Float16)hn;
                outc[ob + q * D2 + c1] = f2bf(hn);
            }
        }
        // 5. one barrier: h writes + gi writes visible; gi reads of buf par done
        bar_lgkm();
    };

    for (int t2 = 0; t2 < S_LEN; t2 += 2) {
        step_body(t2, 0);
        step_body(t2 + 1, 1);
    }

#pragma unroll
    for (int q = 0; q < 4; q++) {
        finals[(size_t)ld * BATCH * HID + (b0 + r0 + q) * HID + c0] = hreg0[q];
        finals[(size_t)ld * BATCH * HID + (b0 + r0 + q) * HID + c1] = hreg1[q];
    }
}

extern "C" void kernel_launch(void* const* d_in, const int* in_sizes, int n_in,
                              void* d_out, int out_size, void* d_ws, size_t ws_size,
                              hipStream_t stream) {
    const float* x     = (const float*)d_in[0];
    const float* h0    = (const float*)d_in[1];
    const float* w_ih0 = (const float*)d_in[2];
    const float* b_ih0 = (const float*)d_in[3];
    const float* w_ih  = (const float*)d_in[4];
    const float* b_ih  = (const float*)d_in[5];
    const float* w_hh  = (const float*)d_in[6];
    const float* b_hh  = (const float*)d_in[7];
    float* out = (float*)d_out;

    char* ws = (char*)d_ws;
    _Float16* whh16 = (_Float16*)(ws + 0);
    u16* wbf0  = (u16*)(ws + 4718592);
    u16* wbfl  = (u16*)(ws + 5111808);
    float* biasT = (float*)(ws + 12976128);
    u16* gi    = (u16*)(ws + 13012992);
    u16* curA  = (u16*)(ws + 113676288);
    u16* curB  = (u16*)(ws + 147230720);

    f32_to_f16_gs<<<(2359296 + 255) / 256, 256, 0, stream>>>(w_hh, whh16, 2359296L);
    f32_to_bf16_gs<<<(196608 + 255) / 256, 256, 0, stream>>>(w_ih0, wbf0, 196608L, 128);
    f32_to_bf16_gs<<<(3932160 + 255) / 256, 256, 0, stream>>>(w_ih, wbfl, 3932160L, 512);
    f32_to_bf16<<<(4194304 + 255) / 256, 256, 0, stream>>>(x, curA, 4194304L);
    add_bias<<<(9216 + 255) / 256, 256, 0, stream>>>(b_ih0, b_ih, b_hh, biasT);

    u16* cin = curA;
    u16* cout_ = curB;
    for (int l = 0; l < 6; l++) {
        int K = l ? 512 : 128;
        const u16* wt = l ? (wbfl + (size_t)(l - 1) * 2 * 768 * 512) : wbf0;
        const float* bi = biasT + (size_t)l * 1536;
        dim3 g(6, 256, 2);
        gemm_mfma<<<g, 256, 0, stream>>>(cin, wt, bi, gi, K);
        scan_mfma<<<dim3(4, 2), 512, 0, stream>>>(whh16, gi, b_hh, h0,
                                                  cout_, out, l);
        u16* tmp = cin; cin = cout_; cout_ = tmp;
    }
}

// Round 9
// 3913.218 us; speedup vs baseline: 2.2600x; 2.2600x over previous
//
#include <hip/hip_runtime.h>
#include <hip/hip_bf16.h>
#include <cstddef>

#define S_LEN 512
#define BATCH 64
#define HID 256
#define G3 768
#define SB (S_LEN*BATCH)
#define D2 512
#define L2E 1.44269504f

typedef unsigned short u16;
typedef _Float16 h2v __attribute__((ext_vector_type(2)));
typedef __attribute__((ext_vector_type(8))) short s16x8;
typedef __attribute__((ext_vector_type(4))) float f32x4;

__device__ __forceinline__ float bf2f(u16 u) {
    return __uint_as_float(((unsigned)u) << 16);
}
__device__ __forceinline__ u16 f2bf(float f) {
    unsigned u = __float_as_uint(f);
    unsigned r = (u + 0x7FFFu + ((u >> 16) & 1u)) >> 16;
    return (u16)r;
}
__device__ __forceinline__ u16 f2h_bits(float f) {
    _Float16 h = (_Float16)f;
    union { _Float16 h; u16 u; } cv; cv.h = h;
    return cv.u;
}
__device__ __forceinline__ h2v u2h(unsigned u) {
    union { unsigned u; h2v h; } cv; cv.u = u;
    return cv.h;
}
__device__ __forceinline__ float dot2f(unsigned w, unsigned h, float acc) {
#if __has_builtin(__builtin_amdgcn_fdot2)
    return __builtin_amdgcn_fdot2(u2h(w), u2h(h), acc, false);
#else
    h2v wv = u2h(w), hv = u2h(h);
    return acc + (float)wv.x * (float)hv.x + (float)wv.y * (float)hv.y;
#endif
}
__device__ __forceinline__ float fast_rcp(float x) {
#if __has_builtin(__builtin_amdgcn_rcpf)
    return __builtin_amdgcn_rcpf(x);
#else
    return 1.f / x;
#endif
}
__device__ __forceinline__ float fast_exp2(float x) {
#if __has_builtin(__builtin_amdgcn_exp2f)
    return __builtin_amdgcn_exp2f(x);
#else
    return __expf(x * 0.69314718f);
#endif
}
__device__ __forceinline__ void gload_lds16(const void* g, void* l) {
    __builtin_amdgcn_global_load_lds((const __attribute__((address_space(1))) void*)g,
                                     (__attribute__((address_space(3))) void*)l, 16, 0, 0);
}

// ---------- prep kernels ----------
__global__ void f32_to_bf16(const float* __restrict__ in, u16* __restrict__ out, long n) {
    long i = (long)blockIdx.x * 256 + threadIdx.x;
    if (i < n) out[i] = f2bf(in[i]);
}
// w_ih scaled: gate rows g<512 ×log2e, g>=512 ×2log2e (exp2 prescale)
__global__ void f32_to_bf16_gs(const float* __restrict__ in, u16* __restrict__ out,
                               long n, int K) {
    long i = (long)blockIdx.x * 256 + threadIdx.x;
    if (i >= n) return;
    int g = (int)((i / K) % 768);
    float sc = (g < 512) ? L2E : (2.f * L2E);
    out[i] = f2bf(in[i] * sc);
}
// w_hh f32 [12][768][256] -> packed half2 [12][128][768] u32, exp2-prescaled per gate
__global__ void pack_whh_f16_gs(const float* __restrict__ in, unsigned* __restrict__ out,
                                long total) {
    long i = (long)blockIdx.x * 256 + threadIdx.x;
    if (i >= total) return;
    long mat = i / (128L * G3);
    long rem = i - mat * (128L * G3);
    int k2 = (int)(rem / G3);
    int g  = (int)(rem - (long)k2 * G3);
    float sc = (g < 512) ? L2E : (2.f * L2E);
    const float* base = in + mat * (768L * 256) + (long)g * 256 + 2 * k2;
    unsigned lo = f2h_bits(base[0] * sc);
    unsigned hi = f2h_bits(base[1] * sc);
    out[i] = lo | (hi << 16);
}
// biasT[l][d][g]: g<512 -> (b_ih+b_hh)*log2e ; g>=512 -> b_ih*2log2e
// (b_hh_n stays INSIDE the r* product, handled in scan)
__global__ void add_bias(const float* __restrict__ bih0, const float* __restrict__ bihl,
                         const float* __restrict__ bhh, float* __restrict__ outb) {
    int i = blockIdx.x * 256 + threadIdx.x;
    if (i >= 6 * 1536) return;
    int l = i / 1536, r = i - l * 1536;
    int g = r % 768;
    float bi = (l == 0) ? bih0[r] : bihl[(l - 1) * 1536 + r];
    outb[i] = (g < 512) ? (bi + bhh[i]) * L2E : bi * (2.f * L2E);
}

// ---------- input GEMM (MFMA) ----------
__global__ __launch_bounds__(256, 2) void gemm_mfma(
    const u16* __restrict__ A,
    const u16* __restrict__ Bt,
    const float* __restrict__ bias,
    u16* __restrict__ Cg,
    int K)
{
    int d = blockIdx.z;
    const u16* Bb = Bt + (size_t)d * 768 * K;
    const float* bi = bias + d * G3;
    u16* Cm = Cg + (size_t)d * SB * G3;

    int n0 = blockIdx.x * 128;
    int m0 = blockIdx.y * 128;
    int tid = threadIdx.x;
    int wave = tid >> 6, lane = tid & 63;
    int wm = wave >> 1, wn = wave & 1;

    __shared__ u16 Asm[128 * 32];
    __shared__ u16 Bsm[128 * 32];

    f32x4 acc[4][4] = {};

    for (int k0 = 0; k0 < K; k0 += 32) {
#pragma unroll
        for (int p = 0; p < 2; p++) {
            int c = p * 256 + wave * 64 + lane;
            int row = c >> 2, kc = c & 3;
            const u16* srcA = A + (size_t)(m0 + row) * K + k0 + kc * 8;
            const u16* srcB = Bb + (size_t)(n0 + row) * K + k0 + kc * 8;
            gload_lds16(srcA, &Asm[(p * 256 + wave * 64) * 8]);
            gload_lds16(srcB, &Bsm[(p * 256 + wave * 64) * 8]);
        }
        __syncthreads();

        s16x8 af[4], bfr[4];
#pragma unroll
        for (int i = 0; i < 4; i++) {
            int arow = wm * 64 + i * 16 + (lane & 15);
            af[i] = *reinterpret_cast<const s16x8*>(&Asm[arow * 32 + (lane >> 4) * 8]);
            int brow = wn * 64 + i * 16 + (lane & 15);
            bfr[i] = *reinterpret_cast<const s16x8*>(&Bsm[brow * 32 + (lane >> 4) * 8]);
        }
#pragma unroll
        for (int i = 0; i < 4; i++)
#pragma unroll
            for (int j = 0; j < 4; j++)
                acc[i][j] = __builtin_amdgcn_mfma_f32_16x16x32_bf16(af[i], bfr[j], acc[i][j], 0, 0, 0);
        __syncthreads();
    }

    int lcol = lane & 15, lrow4 = (lane >> 4) * 4;
#pragma unroll
    for (int i = 0; i < 4; i++) {
#pragma unroll
        for (int j = 0; j < 4; j++) {
            int n = n0 + wn * 64 + j * 16 + lcol;
            float bv = bi[n];
#pragma unroll
            for (int q = 0; q < 4; q++) {
                int m = m0 + wm * 64 + i * 16 + lrow4 + q;
                Cm[(size_t)m * G3 + n] = f2bf(acc[i][j][q] + bv);
            }
        }
    }
}

// ---------- recurrent scan (dot2, split-gate phase 2) ----------
// One block per (batch row, direction); 768 threads; lane tid owns gate tid>>8,
// unit j=tid&255. Weights register-resident (f16 pairs, exp2-prescaled).
// r/z lanes use their OWN accumulator (no gh LDS round-trip); n-lanes keep h f32.
__global__ __launch_bounds__(768, 3) void gru_scan(
    const unsigned* __restrict__ wpack,  // [12][128][768] u32 (half2 pairs), prescaled
    const float* __restrict__ bhh,       // [6][2][768] f32 raw
    const u16* __restrict__ gi,          // [2][SB][768] bf16 prescaled, r/z b_hh folded
    const float* __restrict__ h0,        // [12][64][256] f32
    u16* __restrict__ outc,              // [SB][512] bf16 (scratch on last layer)
    float* __restrict__ finals,          // [12][64][256] f32
    int layer)
{
    int b = blockIdx.x;
    int d = blockIdx.y;
    int tid = threadIdx.x;

    int ld = layer * 2 + d;
    const unsigned* Wp = wpack + (size_t)ld * 128 * G3 + tid;
    const u16* gid = gi + (size_t)d * SB * G3;

    __shared__ float rz_s[512];                    // r[0:256], z[256:512]
    __shared__ alignas(16) _Float16 h16_s[HID];
    __shared__ u16 gi_s[2][G3];

    unsigned wpk[128];
#pragma unroll
    for (int k = 0; k < 128; k++) wpk[k] = Wp[(size_t)k * G3];

    int gate = tid >> 8;          // 0=r, 1=z, 2=n
    int j = tid & 255;

    float hreg = 0.f, bhn = 0.f;
    if (gate == 2) {
        hreg = h0[(size_t)ld * BATCH * HID + b * HID + j];
        bhn = bhh[(size_t)ld * G3 + 512 + j] * (2.f * L2E);
        h16_s[j] = (_Float16)hreg;
    }
    {
        int s0 = d ? (S_LEN - 1) : 0;
        gi_s[0][tid] = gid[((size_t)s0 * BATCH + b) * G3 + tid];
    }
    __syncthreads();

    for (int t = 0; t < S_LEN; t++) {
        int s = d ? (S_LEN - 1 - t) : t;
        // prefetch next step's gi (consumed by ds_write before barrier 1)
        u16 ginext = 0;
        if (t + 1 < S_LEN) {
            int sn = d ? (s - 1) : (s + 1);
            ginext = gid[((size_t)sn * BATCH + b) * G3 + tid];
        }
        // dot: acc = sum_k h[k] * W[k][tid]   (f16 dot2, f32 accum; bias in gi)
        float acc = 0.f;
        const uint4* hp = reinterpret_cast<const uint4*>(h16_s);
#pragma unroll
        for (int k = 0; k < 32; k++) {
            uint4 q = hp[k];
            acc = dot2f(wpk[4 * k + 0], q.x, acc);
            acc = dot2f(wpk[4 * k + 1], q.y, acc);
            acc = dot2f(wpk[4 * k + 2], q.z, acc);
            acc = dot2f(wpk[4 * k + 3], q.w, acc);
        }
        float giv = bf2f(gi_s[t & 1][tid]);   // own slot (prev buffer, stable)
        gi_s[(t + 1) & 1][tid] = ginext;
        // phase A: r/z lanes finish their gate from OWN acc
        if (gate < 2)
            rz_s[tid] = fast_rcp(1.f + fast_exp2(-(giv + acc)));
        __syncthreads();
        // phase B: n-lanes finish n-gate + h update
        if (gate == 2) {
            float r = rz_s[j];
            float z = rz_s[256 + j];
            float xn2 = giv + r * (acc + bhn);              // = 2*log2e * xn
            float n = 1.f - 2.f * fast_rcp(fast_exp2(xn2) + 1.f);
            float hn = n + z * (hreg - n);
            hreg = hn;
            h16_s[j] = (_Float16)hn;
            outc[((size_t)s * BATCH + b) * D2 + d * HID + j] = f2bf(hn);
        }
        __syncthreads();
    }
    if (gate == 2)
        finals[(size_t)ld * BATCH * HID + b * HID + j] = hreg;
}

extern "C" void kernel_launch(void* const* d_in, const int* in_sizes, int n_in,
                              void* d_out, int out_size, void* d_ws, size_t ws_size,
                              hipStream_t stream) {
    const float* x     = (const float*)d_in[0];
    const float* h0    = (const float*)d_in[1];
    const float* w_ih0 = (const float*)d_in[2];
    const float* b_ih0 = (const float*)d_in[3];
    const float* w_ih  = (const float*)d_in[4];
    const float* b_ih  = (const float*)d_in[5];
    const float* w_hh  = (const float*)d_in[6];
    const float* b_hh  = (const float*)d_in[7];
    float* out = (float*)d_out;

    char* ws = (char*)d_ws;
    // wpack u32 [12][128][768]    @ 0           4,718,592
    // wbf0  bf16 [2][768][128]    @ 4,718,592     393,216
    // wbfl  bf16 [5][2][768][512] @ 5,111,808   7,864,320
    // biasT f32 [6][2][768]       @ 12,976,128     36,864
    // gi    bf16 [2][SB][768]     @ 13,012,992 100,663,296
    // curA  bf16 [SB][512]        @ 113,676,288 33,554,432
    // curB  bf16 [SB][512]        @ 147,230,720 33,554,432
    unsigned* wpack = (unsigned*)(ws + 0);
    u16* wbf0  = (u16*)(ws + 4718592);
    u16* wbfl  = (u16*)(ws + 5111808);
    float* biasT = (float*)(ws + 12976128);
    u16* gi    = (u16*)(ws + 13012992);
    u16* curA  = (u16*)(ws + 113676288);
    u16* curB  = (u16*)(ws + 147230720);

    pack_whh_f16_gs<<<(1179648 + 255) / 256, 256, 0, stream>>>(w_hh, wpack, 1179648L);
    f32_to_bf16_gs<<<(196608 + 255) / 256, 256, 0, stream>>>(w_ih0, wbf0, 196608L, 128);
    f32_to_bf16_gs<<<(3932160 + 255) / 256, 256, 0, stream>>>(w_ih, wbfl, 3932160L, 512);
    f32_to_bf16<<<(4194304 + 255) / 256, 256, 0, stream>>>(x, curA, 4194304L);
    add_bias<<<(9216 + 255) / 256, 256, 0, stream>>>(b_ih0, b_ih, b_hh, biasT);

    u16* cin = curA;
    u16* cout_ = curB;
    for (int l = 0; l < 6; l++) {
        int K = l ? 512 : 128;
        const u16* wt = l ? (wbfl + (size_t)(l - 1) * 2 * 768 * 512) : wbf0;
        const float* bi = biasT + (size_t)l * 1536;
        dim3 g(6, 256, 2);
        gemm_mfma<<<g, 256, 0, stream>>>(cin, wt, bi, gi, K);
        gru_scan<<<dim3(64, 2), 768, 0, stream>>>(wpack, b_hh, gi, h0,
                                                  cout_, out, l);
        u16* tmp = cin; cin = cout_; cout_ = tmp;
    }
}